// Round 4
// baseline (594.020 us; speedup 1.0000x reference)
//
#include <hip/hip_runtime.h>
#include <math.h>

#define BATCH  32
#define NPTS   8192
#define NGROUP 512
#define MSIZE  32

#define FPS_THREADS 512
#define SXYZ_FLOATS (NPTS * 3)
#define DYN_LDS_BYTES (SXYZ_FLOATS * 4)

typedef float v2f __attribute__((ext_vector_type(2)));

// ---- DPP helpers (CTRL compile-time const) --------------------------------
// f32 max: bound_ctrl=true -> masked-off lanes read 0; fmax(x,0)=x for x>=0.
template<int CTRL>
__device__ __forceinline__ float dpp_max_f32(float x) {
    int o = __builtin_amdgcn_update_dpp(0, __float_as_int(x), CTRL, 0xF, 0xF, true);
    float f = __int_as_float(o);
    return x > f ? x : f;
}
template<int CTRL>
__device__ __forceinline__ unsigned dpp_min_u32_full(unsigned x) {
    unsigned o = (unsigned)__builtin_amdgcn_update_dpp(0, (int)x, CTRL, 0xF, 0xF, true);
    return o < x ? o : x;
}

__device__ __forceinline__ unsigned long long u64max(unsigned long long a,
                                                     unsigned long long b) {
    return a > b ? a : b;
}

// ---------------------------------------------------------------------------
// FPS: one block/batch, 512 threads (8 waves, 2/SIMD), 16 pts/thread as v2f
// pairs (packed f32 math, bit-exact numpy order, contract off). Ownership
// CONTIGUOUS: thread t owns [16t,16t+16). Per step, ONE barrier.
// Cross-wave reduce: 4 atomic SLOTS (wave w -> gkeys[g%3][w>>1], 2 waves per
// slot) to cut the same-address LDS-atomic serialization tail 8-deep -> 2-deep
// (round-3 model: ~300-400 cyc of the ~1500 cyc/step serial chain). Slots are
// triple-buffered by g%3 with the SAME reset discipline as the verified
// 1-slot version (reset of set (g+1)%3 pre-barrier at step g is after its
// last readers' barrier(g-1) and before its writers' post-barrier(g) start).
// Post-barrier: two independent ds_read_b128 (overlapping latency, same as
// the old single b64) + 3-op u64 max tree -> fi. Key = (wmaxbits<<32)|~widx
// unchanged -> exact np.argmax first-occurrence semantics incl. ties.
// Round-1 lesson respected: reduction stays ATOMIC + pre-barrier; only the
// address fan-out changed. Round-3 lesson: pre-barrier wave tail is hidden by
// skew (tie-tree change was neutral), so the added post-barrier ~20 cyc is
// the only cost here.
// In-loop global stores removed (r3): t0 records fi in s_fi[]; parallel
// epilogue writes out_fps/out_center once.
// ---------------------------------------------------------------------------
__global__ __launch_bounds__(FPS_THREADS, 2)
void fps_kernel(const float* __restrict__ xyz,
                float* __restrict__ out_center,
                float* __restrict__ out_fps)
{
#pragma clang fp contract(off)
    extern __shared__ float sxyz[];                        // [24576]
    __shared__ unsigned long long gkeys[3][4];             // [set][slot]
    __shared__ int s_fi[NGROUP];

    const int b    = blockIdx.x;
    const int t    = threadIdx.x;
    const int lane = t & 63;
    const int wid  = t >> 6;
    const float* bp = xyz + (size_t)b * NPTS * 3;
    const float4* bp4 = reinterpret_cast<const float4*>(bp);
    float4* s4 = reinterpret_cast<float4*>(sxyz);

    // contiguous ownership: thread t owns points 16t..16t+15 (12 float4).
    v2f px2[8], py2[8], pz2[8], dist2[8];
    #pragma unroll
    for (int j = 0; j < 8; ++j) dist2[j] = (v2f){INFINITY, INFINITY};
    #pragma unroll
    for (int q = 0; q < 12; ++q) {
        float4 v = bp4[t * 12 + q];
        s4[t * 12 + q] = v;
        const float vv[4] = {v.x, v.y, v.z, v.w};
        #pragma unroll
        for (int e = 0; e < 4; ++e) {
            const int n  = q * 4 + e;      // 0..47, compile-time
            const int j2 = n / 3;          // point within thread (0..15)
            const int c  = n % 3;          // coord
            const int h  = j2 >> 1;        // v2 slot
            const float val = vv[e];
            if (c == 0) { if (j2 & 1) px2[h].y = val; else px2[h].x = val; }
            else if (c == 1) { if (j2 & 1) py2[h].y = val; else py2[h].x = val; }
            else { if (j2 & 1) pz2[h].y = val; else pz2[h].x = val; }
        }
    }
    if (t < 12) ((unsigned long long*)gkeys)[t] = 0ull;
    if (t == 0) s_fi[0] = 0;
    __syncthreads();   // sxyz + gkeys visible

    int last = 0;
    for (int g = 1; g < NGROUP; ++g) {
        const int slot = g % 3;
        const int nxt  = (g + 1) % 3;
        float lx = sxyz[last*3 + 0];     // broadcast LDS reads
        float ly = sxyz[last*3 + 1];
        float lz = sxyz[last*3 + 2];

        // packed dist update: per element (dx*dx + dy*dy) + dz*dz, then min
        #pragma unroll
        for (int j = 0; j < 8; ++j) {
            v2f dx = px2[j] - lx;
            v2f dy = py2[j] - ly;
            v2f dz = pz2[j] - lz;
            v2f t1 = dx * dx;
            v2f t2 = dy * dy;
            v2f t3 = dz * dz;
            v2f s  = t1 + t2;
            v2f d  = s + t3;
            dist2[j] = __builtin_elementwise_min(dist2[j], d);
        }
        // per-thread max (exact, order-free)
        v2f mm0 = __builtin_elementwise_max(dist2[0], dist2[1]);
        v2f mm1 = __builtin_elementwise_max(dist2[2], dist2[3]);
        v2f mm2 = __builtin_elementwise_max(dist2[4], dist2[5]);
        v2f mm3 = __builtin_elementwise_max(dist2[6], dist2[7]);
        v2f mma = __builtin_elementwise_max(mm0, mm1);
        v2f mmb = __builtin_elementwise_max(mm2, mm3);
        v2f mmc = __builtin_elementwise_max(mma, mmb);
        float m_t = fmaxf(mmc.x, mmc.y);

        // wave max via DPP -> wmax (uniform)
        float m = m_t;
        m = dpp_max_f32<0xB1>(m);     // quad_perm xor1
        m = dpp_max_f32<0x4E>(m);     // quad_perm xor2
        m = dpp_max_f32<0x141>(m);    // row_half_mirror
        m = dpp_max_f32<0x140>(m);    // row_mirror
        m = dpp_max_f32<0x142>(m);    // row_bcast15
        m = dpp_max_f32<0x143>(m);    // row_bcast31
        float wmax = __int_as_float(__builtin_amdgcn_readlane(__float_as_int(m), 63));

        // lowest candidate lane (contiguous ownership => lane order = idx order)
        unsigned long long mask = __ballot(m_t == wmax);
        int l = __ffsll((long long)mask) - 1;

        // lowest j with d[j]==wmax: pair candidates + 3-level min tree
        unsigned cand[8];
        #pragma unroll
        for (int p = 0; p < 8; ++p) {
            unsigned c = 0xFFFFFFFFu;
            c = (dist2[p].y == wmax) ? (unsigned)(2*p + 1) : c;
            c = (dist2[p].x == wmax) ? (unsigned)(2*p)     : c;   // x preferred
            cand[p] = c;
        }
        unsigned q0 = cand[0] < cand[1] ? cand[0] : cand[1];
        unsigned q1 = cand[2] < cand[3] ? cand[2] : cand[3];
        unsigned q2 = cand[4] < cand[5] ? cand[4] : cand[5];
        unsigned q3 = cand[6] < cand[7] ? cand[6] : cand[7];
        unsigned qa = q0 < q1 ? q0 : q1;
        unsigned qb = q2 < q3 ? q2 : q3;
        unsigned lj = qa < qb ? qa : qb;       // <16 on candidate lanes
        unsigned idx = ((unsigned)t << 4) | lj;
        unsigned widx = (unsigned)__builtin_amdgcn_readlane((int)idx, l);

        if (lane == 63) {
            unsigned long long key =
                (((unsigned long long)__float_as_uint(wmax)) << 32) | (unsigned)~widx;
            atomicMax(&gkeys[slot][wid >> 1], key);      // 4 slots, 2 waves each
            if (wid < 4) gkeys[nxt][wid] = 0ull;         // reset next set (pre-barrier)
        }
        __syncthreads();                  // the ONE barrier

        // global winner: max over 4 slots (two overlapping b128 reads)
        const unsigned long long* sk = gkeys[slot];
        ulonglong2 pA = *reinterpret_cast<const ulonglong2*>(&sk[0]);
        ulonglong2 pB = *reinterpret_cast<const ulonglong2*>(&sk[2]);
        unsigned long long km = u64max(u64max(pA.x, pA.y), u64max(pB.x, pB.y));
        int fi = (int)(~(unsigned)km);
        last = fi;
        if (t == 0) s_fi[g] = fi;             // LDS only; no global stores in loop
    }

    // epilogue: thread t <-> group t (512 threads, 512 groups)
    __syncthreads();                          // s_fi[511] visible
    {
        const int g  = t;
        const int fi = s_fi[g];
        out_fps[(size_t)b * NGROUP + g] = (float)fi;
        const size_t o = ((size_t)(b * NGROUP + g)) * 3;
        out_center[o + 0] = sxyz[fi*3 + 0];
        out_center[o + 1] = sxyz[fi*3 + 1];
        out_center[o + 2] = sxyz[fi*3 + 2];
    }
}

// ---------------------------------------------------------------------------
// kNN: round-0 structure (one wave/group, max occupancy — r1 LDS-resident and
// r2 CPW=4 both regressed), now with SOFTWARE-PIPELINED chunk loads: prefetch
// chunk c+1 (wrap &31 keeps addresses in-bounds; last prefetch is dead) before
// computing chunk c, so the ~200-cyc L2 latency overlaps the dist math +
// data-dependent insert scan. Distance math / key truncation / insert order /
// 32-round DPP+shfl pop reduce verbatim -> bit-identical outputs.
// ---------------------------------------------------------------------------
__global__ __launch_bounds__(256)
void knn_kernel(const float* __restrict__ xyz,
                const float* __restrict__ center,
                float* __restrict__ out_nbhd)
{
    const int lane = threadIdx.x & 63;
    const int gid  = blockIdx.x * 4 + (threadIdx.x >> 6);   // 0..16383
    const int b    = gid >> 9;
    const float* bp = xyz + (size_t)b * NPTS * 3;
    const float4* bp4 = reinterpret_cast<const float4*>(bp);

    const float cx = center[(size_t)gid*3+0];
    const float cy = center[(size_t)gid*3+1];
    const float cz = center[(size_t)gid*3+2];

    unsigned kl[4];
    #pragma unroll
    for (int k = 0; k < 4; ++k) kl[k] = 0xFFFFFFFFu;

    // prologue: load chunk 0
    float4 a  = bp4[lane*3 + 0];
    float4 bq = bp4[lane*3 + 1];
    float4 cq = bp4[lane*3 + 2];

    for (int c = 0; c < 32; ++c) {
        // prefetch next chunk (wrap to 0 on last iter: in-bounds, result dead)
        const int nc = (c + 1) & 31;
        const int nf4 = nc * 192 + lane * 3;
        float4 na  = bp4[nf4 + 0];
        float4 nbq = bp4[nf4 + 1];
        float4 ncq = bp4[nf4 + 2];

        unsigned p0 = (unsigned)(c * 256 + lane * 4);
        v2f xA = (v2f){a.x,  a.w},  yA = (v2f){a.y,  bq.x}, zA = (v2f){a.z,  bq.y};
        v2f xB = (v2f){bq.z, cq.y}, yB = (v2f){bq.w, cq.z}, zB = (v2f){cq.x, cq.w};
        v2f dxA = xA - cx, dyA = yA - cy, dzA = zA - cz;
        v2f dxB = xB - cx, dyB = yB - cy, dzB = zB - cz;
        v2f dA = dxA*dxA + dyA*dyA + dzA*dzA;
        v2f dB = dxB*dxB + dyB*dyB + dzB*dzB;
        float ds[4] = {dA.x, dA.y, dB.x, dB.y};
        #pragma unroll
        for (int k = 0; k < 4; ++k) {
            unsigned key = (__float_as_uint(ds[k]) & 0xFFFFE000u) | (p0 + k);
            if (key < kl[3]) {
                kl[3] = key;
                #pragma unroll
                for (int q = 3; q > 0; --q) {
                    if (kl[q] < kl[q-1]) {
                        unsigned tk = kl[q]; kl[q] = kl[q-1]; kl[q-1] = tk;
                    }
                }
            }
        }
        a = na; bq = nbq; cq = ncq;
    }

    int keep = 0;
    #pragma unroll 1
    for (int r = 0; r < MSIZE; ++r) {
        unsigned k = kl[0];
        k = dpp_min_u32_full<0xB1>(k);     // xor1
        k = dpp_min_u32_full<0x4E>(k);     // xor2
        k = dpp_min_u32_full<0x141>(k);    // half mirror
        k = dpp_min_u32_full<0x140>(k);    // mirror -> rows of 16 uniform
        {
            unsigned o = __shfl_xor(k, 16);
            k = o < k ? o : k;
            o = __shfl_xor(k, 32);
            k = o < k ? o : k;
        }
        if (lane == r) keep = (int)(k & 0x1FFFu);
        if (kl[0] == k) {                   // unique (idx embedded)
            kl[0] = kl[1]; kl[1] = kl[2]; kl[2] = kl[3];
            kl[3] = 0xFFFFFFFFu;
        }
    }

    if (lane < MSIZE) {
        size_t o = ((size_t)gid * MSIZE + lane) * 3;
        float x = bp[keep*3+0], y = bp[keep*3+1], z = bp[keep*3+2];
        out_nbhd[o+0] = x - cx;
        out_nbhd[o+1] = y - cy;
        out_nbhd[o+2] = z - cz;
    }
}

// ---------------------------------------------------------------------------
extern "C" void kernel_launch(void* const* d_in, const int* in_sizes, int n_in,
                              void* d_out, int out_size, void* d_ws, size_t ws_size,
                              hipStream_t stream)
{
    const float* xyz = (const float*)d_in[0];
    float* out        = (float*)d_out;
    float* out_nbhd   = out;                                    // 32*512*32*3
    float* out_center = out + (size_t)BATCH*NGROUP*MSIZE*3;     // 32*512*3
    float* out_fps    = out_center + (size_t)BATCH*NGROUP*3;    // 32*512

    hipFuncSetAttribute(reinterpret_cast<const void*>(fps_kernel),
                        hipFuncAttributeMaxDynamicSharedMemorySize,
                        DYN_LDS_BYTES);

    fps_kernel<<<dim3(BATCH), dim3(FPS_THREADS), DYN_LDS_BYTES, stream>>>(xyz, out_center, out_fps);
    knn_kernel<<<dim3(BATCH*NGROUP/4), dim3(256), 0, stream>>>(xyz, out_center, out_nbhd);
}

// Round 5
// 578.327 us; speedup vs baseline: 1.0271x; 1.0271x over previous
//
#include <hip/hip_runtime.h>
#include <math.h>

#define BATCH  32
#define NPTS   8192
#define NGROUP 512
#define MSIZE  32

#define FPS_THREADS 512
#define SXYZ_FLOATS (NPTS * 3)
#define DYN_LDS_BYTES (SXYZ_FLOATS * 4)

typedef float v2f __attribute__((ext_vector_type(2)));

// ---- DPP helpers (CTRL compile-time const) --------------------------------
// f32 max: bound_ctrl=true -> masked-off lanes read 0; fmax(x,0)=x for x>=0.
template<int CTRL>
__device__ __forceinline__ float dpp_max_f32(float x) {
    int o = __builtin_amdgcn_update_dpp(0, __float_as_int(x), CTRL, 0xF, 0xF, true);
    float f = __int_as_float(o);
    return x > f ? x : f;
}
// u32 min with KEEP-OLD semantics: bound_ctrl=false and old=x, so lanes with
// no valid DPP source keep their own value (a 0-inject would poison a MIN).
// Chain xor1,xor2,half_mirror,mirror -> 16-rows uniform; bcast15 merges row
// pairs (lanes 16-31 <- min(r0,r1), 48-63 <- min(r2,r3); others keep own);
// bcast31 sends lane31=min(r0,r1) to lanes 32-63 -> lane 63 = global min.
template<int CTRL>
__device__ __forceinline__ unsigned dpp_min_u32_keep(unsigned x) {
    unsigned o = (unsigned)__builtin_amdgcn_update_dpp((int)x, (int)x, CTRL, 0xF, 0xF, false);
    return o < x ? o : x;
}

// ---------------------------------------------------------------------------
// FPS: EXACT round-0 kernel (best measured 463.7 µs; rounds 1/3/4 proved every
// deviation from this skeleton — post-barrier tree, tie-tree, store-hoist,
// 4-slot atomic — is neutral or negative). One block/batch, 512 threads
// (8 waves, 2/SIMD), 16 pts/thread as v2f pairs (packed f32 math, bit-exact
// numpy order: (dx^2+dy^2)+dz^2, contract off). Ownership CONTIGUOUS. Per
// step, ONE barrier; lane63 atomicMax to a single triple-buffered gkey slot.
// Exact np.argmax first-occurrence semantics incl. ties.
// ---------------------------------------------------------------------------
__global__ __launch_bounds__(FPS_THREADS, 2)
void fps_kernel(const float* __restrict__ xyz,
                float* __restrict__ out_center,
                float* __restrict__ out_fps)
{
#pragma clang fp contract(off)
    extern __shared__ float sxyz[];                        // [24576]
    __shared__ unsigned long long gkey[3];

    const int b    = blockIdx.x;
    const int t    = threadIdx.x;
    const int lane = t & 63;
    const float* bp = xyz + (size_t)b * NPTS * 3;
    const float4* bp4 = reinterpret_cast<const float4*>(bp);
    float4* s4 = reinterpret_cast<float4*>(sxyz);

    // contiguous ownership: thread t owns points 16t..16t+15 (48 floats,
    // 12 float4). Stage into LDS with the same reads.
    v2f px2[8], py2[8], pz2[8], dist2[8];
    {
        float f[48];
        #pragma unroll
        for (int q = 0; q < 12; ++q) {
            float4 v = bp4[t * 12 + q];
            s4[t * 12 + q] = v;
            f[q*4+0] = v.x; f[q*4+1] = v.y; f[q*4+2] = v.z; f[q*4+3] = v.w;
        }
        #pragma unroll
        for (int j = 0; j < 8; ++j) {
            px2[j] = (v2f){f[6*j+0], f[6*j+3]};
            py2[j] = (v2f){f[6*j+1], f[6*j+4]};
            pz2[j] = (v2f){f[6*j+2], f[6*j+5]};
            dist2[j] = (v2f){INFINITY, INFINITY};
        }
    }
    if (t == 0) { gkey[0] = 0; gkey[1] = 0; gkey[2] = 0; }
    __syncthreads();   // sxyz + gkey visible

    if (t == 0) {
        out_fps[(size_t)b * NGROUP] = 0.0f;
        out_center[(size_t)(b * NGROUP) * 3 + 0] = sxyz[0];
        out_center[(size_t)(b * NGROUP) * 3 + 1] = sxyz[1];
        out_center[(size_t)(b * NGROUP) * 3 + 2] = sxyz[2];
    }

    int last = 0;
    for (int g = 1; g < NGROUP; ++g) {
        const int slot = g % 3;
        const int nxt  = (g + 1) % 3;
        float lx = sxyz[last*3 + 0];     // broadcast LDS reads
        float ly = sxyz[last*3 + 1];
        float lz = sxyz[last*3 + 2];

        // packed dist update: per element (dx*dx + dy*dy) + dz*dz, then min
        #pragma unroll
        for (int j = 0; j < 8; ++j) {
            v2f dx = px2[j] - lx;
            v2f dy = py2[j] - ly;
            v2f dz = pz2[j] - lz;
            v2f t1 = dx * dx;
            v2f t2 = dy * dy;
            v2f t3 = dz * dz;
            v2f s  = t1 + t2;
            v2f d  = s + t3;
            dist2[j] = __builtin_elementwise_min(dist2[j], d);
        }
        // per-thread max (exact, order-free)
        v2f mm0 = __builtin_elementwise_max(dist2[0], dist2[1]);
        v2f mm1 = __builtin_elementwise_max(dist2[2], dist2[3]);
        v2f mm2 = __builtin_elementwise_max(dist2[4], dist2[5]);
        v2f mm3 = __builtin_elementwise_max(dist2[6], dist2[7]);
        v2f mma = __builtin_elementwise_max(mm0, mm1);
        v2f mmb = __builtin_elementwise_max(mm2, mm3);
        v2f mmc = __builtin_elementwise_max(mma, mmb);
        float m_t = fmaxf(mmc.x, mmc.y);

        // wave max via DPP -> wmax (uniform, sgpr)
        float m = m_t;
        m = dpp_max_f32<0xB1>(m);     // quad_perm xor1
        m = dpp_max_f32<0x4E>(m);     // quad_perm xor2
        m = dpp_max_f32<0x141>(m);    // row_half_mirror
        m = dpp_max_f32<0x140>(m);    // row_mirror
        m = dpp_max_f32<0x142>(m);    // row_bcast15
        m = dpp_max_f32<0x143>(m);    // row_bcast31
        float wmax = __int_as_float(__builtin_amdgcn_readlane(__float_as_int(m), 63));

        // lowest candidate lane (contiguous ownership => lane order = idx order)
        unsigned long long mask = __ballot(m_t == wmax);
        int l = __ffsll((long long)mask) - 1;

        // each lane: lowest j with d[j]==wmax (descending select chain)
        unsigned lj = 0;
        #pragma unroll
        for (int j = 15; j >= 0; --j) {
            float dj = (j & 1) ? dist2[j >> 1].y : dist2[j >> 1].x;
            lj = (dj == wmax) ? (unsigned)j : lj;
        }
        unsigned idx = ((unsigned)t << 4) | lj;
        unsigned widx = (unsigned)__builtin_amdgcn_readlane((int)idx, l);

        if (lane == 63) {
            unsigned long long key =
                (((unsigned long long)__float_as_uint(wmax)) << 32) | (unsigned)~widx;
            atomicMax(&gkey[slot], key);
            if (t == 63) gkey[nxt] = 0;   // reset slot for step g+1 (pre-barrier)
        }
        __syncthreads();                  // the ONE barrier

        unsigned long long kq = gkey[slot];   // broadcast b64 read
        int fi = (int)(~(unsigned)kq);
        last = fi;
        if (t == 0) {
            out_fps[(size_t)b * NGROUP + g] = (float)fi;
            out_center[((size_t)(b * NGROUP + g)) * 3 + 0] = sxyz[fi*3 + 0];
            out_center[((size_t)(b * NGROUP + g)) * 3 + 1] = sxyz[fi*3 + 1];
            out_center[((size_t)(b * NGROUP + g)) * 3 + 2] = sxyz[fi*3 + 2];
        }
    }
}

// ---------------------------------------------------------------------------
// kNN: round-0 structure (one wave/group, max occupancy — r1 LDS-resident,
// r2 CPW=4, r4 prefetch ALL regressed; knn is VALU-issue-bound + serial
// cross-lane latency). ONE change vs round-0: the per-round min-reduce is now
// a 6-stage full-wave DPP chain ending in lane 63 + readlane(63), replacing
// 4 DPP + 2 __shfl_xor (each shfl = ds_bpermute LDS round-trip on the
// 32-round dependent chain ≈ 2k exposed cyc/wave). u32-min uses keep-old
// DPP (bound_ctrl=false, old=x) — 0-inject would poison a min. Same kmin
// broadcast, same unique-key pop semantics -> bit-identical outputs.
// ---------------------------------------------------------------------------
__global__ __launch_bounds__(256)
void knn_kernel(const float* __restrict__ xyz,
                const float* __restrict__ center,
                float* __restrict__ out_nbhd)
{
    const int lane = threadIdx.x & 63;
    const int gid  = blockIdx.x * 4 + (threadIdx.x >> 6);   // 0..16383
    const int b    = gid >> 9;
    const float* bp = xyz + (size_t)b * NPTS * 3;
    const float4* bp4 = reinterpret_cast<const float4*>(bp);

    const float cx = center[(size_t)gid*3+0];
    const float cy = center[(size_t)gid*3+1];
    const float cz = center[(size_t)gid*3+2];

    unsigned kl[4];
    #pragma unroll
    for (int k = 0; k < 4; ++k) kl[k] = 0xFFFFFFFFu;

    for (int c = 0; c < 32; ++c) {
        int f4 = c * 192 + lane * 3;
        float4 a  = bp4[f4+0];
        float4 bq = bp4[f4+1];
        float4 cq = bp4[f4+2];
        unsigned p0 = (unsigned)(c * 256 + lane * 4);
        v2f xA = (v2f){a.x,  a.w},  yA = (v2f){a.y,  bq.x}, zA = (v2f){a.z,  bq.y};
        v2f xB = (v2f){bq.z, cq.y}, yB = (v2f){bq.w, cq.z}, zB = (v2f){cq.x, cq.w};
        v2f dxA = xA - cx, dyA = yA - cy, dzA = zA - cz;
        v2f dxB = xB - cx, dyB = yB - cy, dzB = zB - cz;
        v2f dA = dxA*dxA + dyA*dyA + dzA*dzA;
        v2f dB = dxB*dxB + dyB*dyB + dzB*dzB;
        float ds[4] = {dA.x, dA.y, dB.x, dB.y};
        #pragma unroll
        for (int k = 0; k < 4; ++k) {
            unsigned key = (__float_as_uint(ds[k]) & 0xFFFFE000u) | (p0 + k);
            if (key < kl[3]) {
                kl[3] = key;
                #pragma unroll
                for (int q = 3; q > 0; --q) {
                    if (kl[q] < kl[q-1]) {
                        unsigned tk = kl[q]; kl[q] = kl[q-1]; kl[q-1] = tk;
                    }
                }
            }
        }
    }

    int keep = 0;
    #pragma unroll 1
    for (int r = 0; r < MSIZE; ++r) {
        unsigned k = kl[0];
        k = dpp_min_u32_keep<0xB1>(k);     // quad_perm xor1
        k = dpp_min_u32_keep<0x4E>(k);     // quad_perm xor2
        k = dpp_min_u32_keep<0x141>(k);    // row_half_mirror
        k = dpp_min_u32_keep<0x140>(k);    // row_mirror -> rows of 16 uniform
        k = dpp_min_u32_keep<0x142>(k);    // row_bcast15 (keep-old on rows 0,2)
        k = dpp_min_u32_keep<0x143>(k);    // row_bcast31 -> lane 63 = global min
        unsigned kmin = (unsigned)__builtin_amdgcn_readlane((int)k, 63);
        if (lane == r) keep = (int)(kmin & 0x1FFFu);
        if (kl[0] == kmin) {                // unique (idx embedded)
            kl[0] = kl[1]; kl[1] = kl[2]; kl[2] = kl[3];
            kl[3] = 0xFFFFFFFFu;
        }
    }

    if (lane < MSIZE) {
        size_t o = ((size_t)gid * MSIZE + lane) * 3;
        float x = bp[keep*3+0], y = bp[keep*3+1], z = bp[keep*3+2];
        out_nbhd[o+0] = x - cx;
        out_nbhd[o+1] = y - cy;
        out_nbhd[o+2] = z - cz;
    }
}

// ---------------------------------------------------------------------------
extern "C" void kernel_launch(void* const* d_in, const int* in_sizes, int n_in,
                              void* d_out, int out_size, void* d_ws, size_t ws_size,
                              hipStream_t stream)
{
    const float* xyz = (const float*)d_in[0];
    float* out        = (float*)d_out;
    float* out_nbhd   = out;                                    // 32*512*32*3
    float* out_center = out + (size_t)BATCH*NGROUP*MSIZE*3;     // 32*512*3
    float* out_fps    = out_center + (size_t)BATCH*NGROUP*3;    // 32*512

    hipFuncSetAttribute(reinterpret_cast<const void*>(fps_kernel),
                        hipFuncAttributeMaxDynamicSharedMemorySize,
                        DYN_LDS_BYTES);

    fps_kernel<<<dim3(BATCH), dim3(FPS_THREADS), DYN_LDS_BYTES, stream>>>(xyz, out_center, out_fps);
    knn_kernel<<<dim3(BATCH*NGROUP/4), dim3(256), 0, stream>>>(xyz, out_center, out_nbhd);
}